// Round 8
// baseline (2344.211 us; speedup 1.0000x reference)
//
#include <hip/hip_runtime.h>
#include <hip/hip_bf16.h>

#define B_N 16384
#define D_N 512
#define M_N 16

typedef __attribute__((ext_vector_type(4))) float  f32x4;
typedef __attribute__((ext_vector_type(8))) short  s16x8;

__device__ __forceinline__ short bf16_of(float f) {
  union { float f; unsigned u; } v; v.f = f;
  unsigned r = v.u + 0x7fffu + ((v.u >> 16) & 1u);  // RNE
  return (short)(r >> 16);
}
__device__ __forceinline__ float f32_of_bf16(unsigned short u) {
  union { unsigned u; float f; } v; v.u = ((unsigned)u) << 16; return v.f;
}
__device__ __forceinline__ void gload_lds16(const void* g, void* l) {
  __builtin_amdgcn_global_load_lds(
      (const __attribute__((address_space(1))) unsigned*)g,
      (__attribute__((address_space(3))) unsigned*)l, 16, 0, 0);
}

#define MFMA_ACC(d, x, y) d = __builtin_amdgcn_mfma_f32_16x16x32_bf16(x, y, d, 0, 0, 0)
#define MFMA_Z(d, x, y)   d = __builtin_amdgcn_mfma_f32_16x16x32_bf16(x, y, FZERO, 0, 0, 0)

// ---------------------------------------------------------------------------
// Kernel 1 (fused): Psib[m][e][d] = bf16(Psi[m][d][e]) pre-swizzled, AND
// wT[d,m] = sum_e Psi[m,d,e]*gt[m,e] (f32 exact path for gates).
// ---------------------------------------------------------------------------
__global__ void k_trw(const float* __restrict__ Psi, const float* __restrict__ gt,
                      short* __restrict__ Psib, float* __restrict__ wT) {
  int m = blockIdx.y, d0 = blockIdx.x << 6;
  __shared__ float tile[64][65];
  __shared__ float gs[D_N];
  int t = threadIdx.x;
  for (int i = t; i < D_N; i += 256) gs[i] = gt[m * D_N + i];
  int r = t >> 2, q = t & 3;
  float wacc = 0.f;
  const float* src = Psi + (size_t)m * D_N * D_N;
  short* dst = Psib + (size_t)m * D_N * D_N;
  for (int e0 = 0; e0 < D_N; e0 += 64) {
    __syncthreads();
    #pragma unroll
    for (int j = 0; j < 4; ++j) {
      int idx = t + (j << 8);
      int rr = idx >> 4, c4 = idx & 15;
      *(f32x4*)&tile[rr][c4 * 4] = *(const f32x4*)(src + (size_t)(d0 + rr) * D_N + e0 + c4 * 4);
    }
    __syncthreads();
    #pragma unroll
    for (int k = 0; k < 16; ++k) wacc += tile[r][q * 16 + k] * gs[e0 + q * 16 + k];
    #pragma unroll
    for (int it = 0; it < 2; ++it) {
      int idx = t + (it << 8);
      int el = idx >> 3, jb = idx & 7;
      int e = e0 + el;
      s16x8 o;
      #pragma unroll
      for (int k = 0; k < 8; ++k) o[k] = bf16_of(tile[jb * 8 + k][el]);
      int db = jb ^ (e & 7);
      *(s16x8*)(dst + (size_t)e * D_N + d0 + db * 8) = o;
    }
  }
  wacc += __shfl_xor(wacc, 1);
  wacc += __shfl_xor(wacc, 2);
  if (q == 0) wT[(d0 + r) * M_N + m] = wacc;
}

// ---------------------------------------------------------------------------
// Kernel 2 (fused): gates (bf16) + pre-swizzled bf16 z, one z read.
// ---------------------------------------------------------------------------
__global__ void k_gz(const float* __restrict__ z, const float* __restrict__ wT,
                     short* __restrict__ zb, unsigned short* __restrict__ gatesb) {
  __shared__ float zs[16][D_N];
  int t = threadIdx.x;
  size_t b0 = (size_t)blockIdx.x * 16;
  #pragma unroll
  for (int j = 0; j < 8; ++j) {
    int idx = t + (j << 8);
    int r = idx >> 7, c4 = idx & 127;
    *(f32x4*)&zs[r][c4 * 4] = *(const f32x4*)(z + (b0 + r) * D_N + c4 * 4);
  }
  __syncthreads();
  int r = t >> 4, m = t & 15;
  float s0 = 0.f, s1 = 0.f, s2 = 0.f, s3 = 0.f;
  #pragma unroll 4
  for (int e = 0; e < D_N; e += 4) {
    s0 += zs[r][e + 0] * wT[(e + 0) * M_N + m];
    s1 += zs[r][e + 1] * wT[(e + 1) * M_N + m];
    s2 += zs[r][e + 2] * wT[(e + 2) * M_N + m];
    s3 += zs[r][e + 3] * wT[(e + 3) * M_N + m];
  }
  float s = (s0 + s1) + (s2 + s3);
  float sig = 1.f / (1.f + expf(-s));
  gatesb[(b0 + r) * M_N + m] = (unsigned short)bf16_of(fmaxf(2.f * sig - 1.f, 0.f));
  #pragma unroll
  for (int j = 0; j < 4; ++j) {
    int idx = t + (j << 8);
    int rr = idx >> 6, blk = idx & 63;
    int chunk = blk >> 3, ib = blk & 7;
    int sb = ib ^ (rr & 7);
    const float* sp = &zs[rr][chunk * 64 + sb * 8];
    s16x8 o;
    #pragma unroll
    for (int k = 0; k < 8; ++k) o[k] = bf16_of(sp[k]);
    *(s16x8*)(zb + (b0 + rr) * D_N + blk * 8) = o;
  }
}

// ---------------------------------------------------------------------------
// Kernel 3: GEMM dz^T-tiles = sum_m g_m * (Psi_m^T @ z^T).  256(b)x128(e),
// 8 waves, d-OUTER / m-INNER.  This round: dc-outer loop with FULLY UNROLLED
// 16-step m-sweep (m, B-buf index, gate offsets all compile-time), processed
// as 8 PAIRS of steps with ONE barrier per pair (fold of s0 overlaps MFMA of
// s1; waves can drift within the region).  NBUF=4 B, counted vmcnt.
// ---------------------------------------------------------------------------
__global__ __launch_bounds__(512, 2) void k_gemm(
    const char* __restrict__ zb, const unsigned short* __restrict__ gatesb,
    const char* __restrict__ pb, float* __restrict__ dz) {
  // A bufs 2x32KB @0 | B bufs 4x16KB @65536 | gates f32 16KB @131072
  __shared__ __align__(128) char smem[147456];
  float* glf = (float*)(smem + 131072);

  const int tid = threadIdx.x;
  const int lane = tid & 63;
  const int wid = tid >> 6;
  const int wr = wid >> 1;             // b-block (64 rows of 256)
  const int wc = wid & 1;              // e-block (64 cols of 128)
  const int bid = blockIdx.x;
  const int xcd = bid & 7;
  const int g8 = bid >> 3;
  const int bcol = g8 & 3;
  const int brow = xcd * 8 + (g8 >> 2);  // A-centric XCD map (L2-resident z)

  // ---- gates -> LDS [m][256 rows] f32 (converted once)
  {
    s16x8 gv = *(const s16x8*)(gatesb + ((size_t)brow << 12) + ((size_t)tid << 3));
    int row = tid >> 1, mbase = (tid & 1) << 3;
    #pragma unroll
    for (int k = 0; k < 8; ++k)
      glf[(mbase + k) * 256 + row] = f32_of_bf16((unsigned short)gv[k]);
  }

  const int rsub = lane >> 3, cbyte = (lane & 7) << 4;

  auto stageA = [&](int ab, int dc) {     // 4 loads: 256 rows x 128B d-chunk
    #pragma unroll
    for (int j = 0; j < 4; ++j) {
      const char* g = zb + (((size_t)(brow * 256 + wid * 8 + j * 64 + rsub)) << 10)
                      + (dc << 7) + cbyte;
      gload_lds16(g, smem + ab * 32768 + (wid << 10) + (j << 13));
    }
  };
  auto stageB = [&](int m, int dc, int q) {  // 2 loads: 128 e-rows x 128B
    #pragma unroll
    for (int j = 0; j < 2; ++j) {
      const char* g = pb + (((size_t)(m * 512 + bcol * 128 + wid * 8 + j * 64 + rsub)) << 10)
                      + (dc << 7) + cbyte;
      gload_lds16(g, smem + 65536 + q * 16384 + (wid << 10) + (j << 13));
    }
  };

  const int lrow = lane & 15;
  const int swz = (lrow & 7) << 4;
  const int kq16 = (((lane >> 4) << 4)) ^ swz;
  const int offY = ((wr * 64 + lrow) << 7) + kq16;   // z frags (y operand)
  const int offX = ((wc * 64 + lrow) << 7) + kq16;   // Psi frags (x operand)
  const float* gbase = glf + wr * 64 + lrow;         // + m*256 + j*16 (imm)

  f32x4 acc[4][4] = {};
  s16x8 areg[4][2];
  const f32x4 FZERO = {0.f, 0.f, 0.f, 0.f};

  // ---- prologue: A(dc0), B(m=0,1); drain; barrier
  stageA(0, 0);
  stageB(0, 0, 0);
  stageB(1, 0, 1);
  asm volatile("s_waitcnt vmcnt(0) lgkmcnt(0)" ::: "memory");
  __builtin_amdgcn_s_barrier();

  for (int dc = 0; dc < 8; ++dc) {
    const char* abase = smem + (dc & 1) * 32768;
    #pragma unroll
    for (int mp = 0; mp < 8; ++mp) {                 // unrolled: m compile-time
      const int m0 = 2 * mp, m1 = 2 * mp + 1;
      const char* b0 = smem + 65536 + (m0 & 3) * 16384;
      const char* b1 = smem + 65536 + (m1 & 3) * 16384;
      f32x4 accm[4][4];
      s16x8 bx0[4], by0[4], bx1[4], by1[4];
      float g0[4], g1[4];

      if (mp == 0) {                                 // z frags for this d-chunk
        #pragma unroll
        for (int j = 0; j < 4; ++j) {
          areg[j][0] = *(const s16x8*)(abase + (offY + j * 2048));
          areg[j][1] = *(const s16x8*)(abase + ((offY + j * 2048) ^ 64));
        }
      }
      // ---- step s0: reads + stage + 32 MFMA + fold
      #pragma unroll
      for (int i = 0; i < 4; ++i) {
        bx0[i] = *(const s16x8*)(b0 + (offX + i * 2048));
        by0[i] = *(const s16x8*)(b0 + ((offX + i * 2048) ^ 64));
      }
      #pragma unroll
      for (int j = 0; j < 4; ++j) g0[j] = gbase[m0 * 256 + j * 16];
      {
        const int mA = (m0 + 2) & 15;                // stage s0+2 (may roll dc)
        const int dcn = dc + ((m0 + 2) >> 4);
        if (dcn < 8) stageB(mA, dcn, (m0 + 2) & 3);
      }
      __builtin_amdgcn_s_setprio(1);
      #pragma unroll
      for (int i = 0; i < 4; ++i)
        #pragma unroll
        for (int j = 0; j < 4; ++j)
          MFMA_Z(accm[i][j], bx0[i], areg[j][0]);
      #pragma unroll
      for (int i = 0; i < 4; ++i)
        #pragma unroll
        for (int j = 0; j < 4; ++j)
          MFMA_ACC(accm[i][j], by0[i], areg[j][1]);
      __builtin_amdgcn_s_setprio(0);
      #pragma unroll
      for (int i = 0; i < 4; ++i)
        #pragma unroll
        for (int j = 0; j < 4; ++j)
          #pragma unroll
          for (int jj = 0; jj < 4; ++jj)
            acc[i][j][jj] = fmaf(g0[j], accm[i][j][jj], acc[i][j][jj]);

      // ---- step s1: reads + stage + 32 MFMA + fold
      #pragma unroll
      for (int i = 0; i < 4; ++i) {
        bx1[i] = *(const s16x8*)(b1 + (offX + i * 2048));
        by1[i] = *(const s16x8*)(b1 + ((offX + i * 2048) ^ 64));
      }
      #pragma unroll
      for (int j = 0; j < 4; ++j) g1[j] = gbase[m1 * 256 + j * 16];
      {
        const int mB = (m0 + 3) & 15;                // stage s0+3
        const int dcn = dc + ((m0 + 3) >> 4);
        if (dcn < 8) stageB(mB, dcn, (m0 + 3) & 3);
      }
      if (mp == 1 && dc < 7) stageA((dc & 1) ^ 1, dc + 1);
      __builtin_amdgcn_s_setprio(1);
      #pragma unroll
      for (int i = 0; i < 4; ++i)
        #pragma unroll
        for (int j = 0; j < 4; ++j)
          MFMA_Z(accm[i][j], bx1[i], areg[j][0]);
      #pragma unroll
      for (int i = 0; i < 4; ++i)
        #pragma unroll
        for (int j = 0; j < 4; ++j)
          MFMA_ACC(accm[i][j], by1[i], areg[j][1]);
      __builtin_amdgcn_s_setprio(0);
      #pragma unroll
      for (int i = 0; i < 4; ++i)
        #pragma unroll
        for (int j = 0; j < 4; ++j)
          #pragma unroll
          for (int jj = 0; jj < 4; ++jj)
            acc[i][j][jj] = fmaf(g1[j], accm[i][j][jj], acc[i][j][jj]);

      // ---- pair end: counted wait (A-stage leaves 4 in flight), barrier
      if (mp == 1 && dc < 7)
        asm volatile("s_waitcnt vmcnt(4)" ::: "memory");
      else
        asm volatile("s_waitcnt vmcnt(0)" ::: "memory");
      __builtin_amdgcn_s_barrier();
    }
  }

  // ---- epilogue: acc[i][j][jj] = dzT[e][b]
  #pragma unroll
  for (int i = 0; i < 4; ++i) {
    int e = bcol * 128 + wc * 64 + i * 16 + ((lane >> 4) << 2);
    #pragma unroll
    for (int j = 0; j < 4; ++j) {
      size_t b = (size_t)brow * 256 + wr * 64 + j * 16 + lrow;
      *(f32x4*)(dz + b * D_N + e) = acc[i][j];
    }
  }
}

// ---------------------------------------------------------------------------
extern "C" void kernel_launch(void* const* d_in, const int* in_sizes, int n_in,
                              void* d_out, int out_size, void* d_ws, size_t ws_size,
                              hipStream_t stream) {
  const float* z   = (const float*)d_in[1];
  const float* Psi = (const float*)d_in[2];
  const float* gt  = (const float*)d_in[3];
  float* dz = (float*)d_out;

  // ws: wT 32KB | gatesb 512KB | Psib 8MB | zb16 16MB  (~24.5MB)
  float* wT = (float*)d_ws;
  unsigned short* gatesb = (unsigned short*)((char*)d_ws + 32768);
  short* Psib = (short*)((char*)d_ws + 32768 + 524288);
  short* zb16 = Psib + (size_t)M_N * D_N * D_N;

  k_trw <<<dim3(8, M_N), dim3(256), 0, stream>>>(Psi, gt, Psib, wT);
  k_gz  <<<dim3(B_N / 16), dim3(256), 0, stream>>>(z, wT, zb16, gatesb);
  k_gemm<<<dim3(256), dim3(512), 0, stream>>>((const char*)zb16, gatesb,
                                              (const char*)Psib, dz);
}

// Round 9
// 183.135 us; speedup vs baseline: 12.8005x; 12.8005x over previous
//
#include <hip/hip_runtime.h>
#include <hip/hip_bf16.h>

#define B_N 16384
#define D_N 512
#define M_N 16

typedef __attribute__((ext_vector_type(4))) float  f32x4;
typedef __attribute__((ext_vector_type(2))) float  f32x2;
typedef __attribute__((ext_vector_type(8))) short  s16x8;

__device__ __forceinline__ short bf16_of(float f) {
  union { float f; unsigned u; } v; v.f = f;
  unsigned r = v.u + 0x7fffu + ((v.u >> 16) & 1u);  // RNE
  return (short)(r >> 16);
}
__device__ __forceinline__ float f32_of_bf16(unsigned short u) {
  union { unsigned u; float f; } v; v.u = ((unsigned)u) << 16; return v.f;
}
__device__ __forceinline__ void gload_lds16(const void* g, void* l) {
  __builtin_amdgcn_global_load_lds(
      (const __attribute__((address_space(1))) unsigned*)g,
      (__attribute__((address_space(3))) unsigned*)l, 16, 0, 0);
}

#define MFMA_ACC(d, x, y) d = __builtin_amdgcn_mfma_f32_16x16x32_bf16(x, y, d, 0, 0, 0)
#define MFMA_Z(d, x, y)   d = __builtin_amdgcn_mfma_f32_16x16x32_bf16(x, y, FZERO, 0, 0, 0)

// ---------------------------------------------------------------------------
// Kernel 1 (fused): Psib[m][e][d] = bf16(Psi[m][d][e]) pre-swizzled, AND
// wT[d,m] = sum_e Psi[m,d,e]*gt[m,e] (f32 exact path for gates).
// ---------------------------------------------------------------------------
__global__ void k_trw(const float* __restrict__ Psi, const float* __restrict__ gt,
                      short* __restrict__ Psib, float* __restrict__ wT) {
  int m = blockIdx.y, d0 = blockIdx.x << 6;
  __shared__ float tile[64][65];
  __shared__ float gs[D_N];
  int t = threadIdx.x;
  for (int i = t; i < D_N; i += 256) gs[i] = gt[m * D_N + i];
  int r = t >> 2, q = t & 3;
  float wacc = 0.f;
  const float* src = Psi + (size_t)m * D_N * D_N;
  short* dst = Psib + (size_t)m * D_N * D_N;
  for (int e0 = 0; e0 < D_N; e0 += 64) {
    __syncthreads();
    #pragma unroll
    for (int j = 0; j < 4; ++j) {
      int idx = t + (j << 8);
      int rr = idx >> 4, c4 = idx & 15;
      *(f32x4*)&tile[rr][c4 * 4] = *(const f32x4*)(src + (size_t)(d0 + rr) * D_N + e0 + c4 * 4);
    }
    __syncthreads();
    #pragma unroll
    for (int k = 0; k < 16; ++k) wacc += tile[r][q * 16 + k] * gs[e0 + q * 16 + k];
    #pragma unroll
    for (int it = 0; it < 2; ++it) {
      int idx = t + (it << 8);
      int el = idx >> 3, jb = idx & 7;
      int e = e0 + el;
      s16x8 o;
      #pragma unroll
      for (int k = 0; k < 8; ++k) o[k] = bf16_of(tile[jb * 8 + k][el]);
      int db = jb ^ (e & 7);
      *(s16x8*)(dst + (size_t)e * D_N + d0 + db * 8) = o;
    }
  }
  wacc += __shfl_xor(wacc, 1);
  wacc += __shfl_xor(wacc, 2);
  if (q == 0) wT[(d0 + r) * M_N + m] = wacc;
}

// ---------------------------------------------------------------------------
// Kernel 2 (fused): gates (bf16) + pre-swizzled bf16 z, one z read.
// ---------------------------------------------------------------------------
__global__ void k_gz(const float* __restrict__ z, const float* __restrict__ wT,
                     short* __restrict__ zb, unsigned short* __restrict__ gatesb) {
  __shared__ float zs[16][D_N];
  int t = threadIdx.x;
  size_t b0 = (size_t)blockIdx.x * 16;
  #pragma unroll
  for (int j = 0; j < 8; ++j) {
    int idx = t + (j << 8);
    int r = idx >> 7, c4 = idx & 127;
    *(f32x4*)&zs[r][c4 * 4] = *(const f32x4*)(z + (b0 + r) * D_N + c4 * 4);
  }
  __syncthreads();
  int r = t >> 4, m = t & 15;
  float s0 = 0.f, s1 = 0.f, s2 = 0.f, s3 = 0.f;
  #pragma unroll 4
  for (int e = 0; e < D_N; e += 4) {
    s0 += zs[r][e + 0] * wT[(e + 0) * M_N + m];
    s1 += zs[r][e + 1] * wT[(e + 1) * M_N + m];
    s2 += zs[r][e + 2] * wT[(e + 2) * M_N + m];
    s3 += zs[r][e + 3] * wT[(e + 3) * M_N + m];
  }
  float s = (s0 + s1) + (s2 + s3);
  float sig = 1.f / (1.f + expf(-s));
  gatesb[(b0 + r) * M_N + m] = (unsigned short)bf16_of(fmaxf(2.f * sig - 1.f, 0.f));
  #pragma unroll
  for (int j = 0; j < 4; ++j) {
    int idx = t + (j << 8);
    int rr = idx >> 6, blk = idx & 63;
    int chunk = blk >> 3, ib = blk & 7;
    int sb = ib ^ (rr & 7);
    const float* sp = &zs[rr][chunk * 64 + sb * 8];
    s16x8 o;
    #pragma unroll
    for (int k = 0; k < 8; ++k) o[k] = bf16_of(sp[k]);
    *(s16x8*)(zb + (b0 + rr) * D_N + blk * 8) = o;
  }
}

// ---------------------------------------------------------------------------
// Kernel 3: GEMM dz^T-tiles = sum_m g_m * (Psi_m^T @ z^T).  256(b)x128(e),
// 8 waves, d-OUTER / m-INNER (z frags reg-cached per d-chunk).
// Round 9: TWO m-steps per barrier region (64 barriers, runtime indices,
// loop pinned rolled), staging issued at region top (full-pair latency cover
// before the end-of-pair drain), packed-f32 fold (v_pk_fma_f32).
// ---------------------------------------------------------------------------
__global__ __launch_bounds__(512, 2) void k_gemm(
    const char* __restrict__ zb, const unsigned short* __restrict__ gatesb,
    const char* __restrict__ pb, float* __restrict__ dz) {
  // A bufs 2x32KB @0 | B bufs 4x16KB @65536 | gates f32 16KB @131072
  __shared__ __align__(128) char smem[147456];
  float* glf = (float*)(smem + 131072);

  const int tid = threadIdx.x;
  const int lane = tid & 63;
  const int wid = tid >> 6;
  const int wr = wid >> 1;             // b-block (64 rows of 256)
  const int wc = wid & 1;              // e-block (64 cols of 128)
  const int bid = blockIdx.x;
  const int xcd = bid & 7;
  const int g8 = bid >> 3;
  const int bcol = g8 & 3;
  const int brow = xcd * 8 + (g8 >> 2);  // A-centric XCD map (L2-resident z)

  // ---- gates -> LDS [m][256 rows] f32 (converted once)
  {
    s16x8 gv = *(const s16x8*)(gatesb + ((size_t)brow << 12) + ((size_t)tid << 3));
    int row = tid >> 1, mbase = (tid & 1) << 3;
    #pragma unroll
    for (int k = 0; k < 8; ++k)
      glf[(mbase + k) * 256 + row] = f32_of_bf16((unsigned short)gv[k]);
  }

  const int rsub = lane >> 3, cbyte = (lane & 7) << 4;

  auto stageA = [&](int ab, int dc) {     // 4 loads: 256 rows x 128B d-chunk
    #pragma unroll
    for (int j = 0; j < 4; ++j) {
      const char* g = zb + (((size_t)(brow * 256 + wid * 8 + j * 64 + rsub)) << 10)
                      + (dc << 7) + cbyte;
      gload_lds16(g, smem + ab * 32768 + (wid << 10) + (j << 13));
    }
  };
  auto stageB = [&](int m, int dc, int q) {  // 2 loads: 128 e-rows x 128B
    #pragma unroll
    for (int j = 0; j < 2; ++j) {
      const char* g = pb + (((size_t)(m * 512 + bcol * 128 + wid * 8 + j * 64 + rsub)) << 10)
                      + (dc << 7) + cbyte;
      gload_lds16(g, smem + 65536 + q * 16384 + (wid << 10) + (j << 13));
    }
  };

  const int lrow = lane & 15;
  const int swz = (lrow & 7) << 4;
  const int kq16 = (((lane >> 4) << 4)) ^ swz;
  const int offY = ((wr * 64 + lrow) << 7) + kq16;   // z frags (y operand)
  const int offX = ((wc * 64 + lrow) << 7) + kq16;   // Psi frags (x operand)
  const float* gbase = glf + wr * 64 + lrow;         // + m*256 + j*16

  f32x4 acc[4][4] = {};
  f32x4 accm[4][4];
  s16x8 areg[4][2];
  s16x8 bx[4], by[4];
  const f32x4 FZERO = {0.f, 0.f, 0.f, 0.f};

  // ---- prologue: A(dc0), B(m=0,1); drain; barrier
  stageA(0, 0);
  stageB(0, 0, 0);
  stageB(1, 0, 1);
  asm volatile("s_waitcnt vmcnt(0) lgkmcnt(0)" ::: "memory");
  __builtin_amdgcn_s_barrier();

  #pragma unroll 1
  for (int dc = 0; dc < 8; ++dc) {
    const char* abase = smem + (dc & 1) * 32768;
    #pragma unroll 1
    for (int mp = 0; mp < 8; ++mp) {
      const int m0 = 2 * mp, m1 = m0 + 1;
      const int q0 = (mp & 1) << 1;              // buffers q0, q0+1 this pair
      const char* b0 = smem + 65536 + (q0 << 14);
      const char* b1 = b0 + 16384;

      // ---- region top: stage pair P+1 (consumed after next barrier; the
      //      end-of-pair vmcnt(0) drain comes a full pair (~2000cy) later)
      {
        const int s2 = dc * 16 + m0 + 2;
        if (s2 + 1 < 128) {
          stageB((m0 + 2) & 15, s2 >> 4, q0 ^ 2);
          stageB((m0 + 3) & 15, (s2 + 1) >> 4, (q0 ^ 2) + 1);
        }
        if (mp == 5 && dc < 7) stageA((dc & 1) ^ 1, dc + 1);
      }

      // ---- z frags for this d-chunk (first pair only)
      if (mp == 0) {
        #pragma unroll
        for (int j = 0; j < 4; ++j) {
          areg[j][0] = *(const s16x8*)(abase + (offY + j * 2048));
          areg[j][1] = *(const s16x8*)(abase + ((offY + j * 2048) ^ 64));
        }
      }

      float g0[4], g1[4];
      #pragma unroll
      for (int j = 0; j < 4; ++j) g0[j] = gbase[m0 * 256 + j * 16];
      #pragma unroll
      for (int j = 0; j < 4; ++j) g1[j] = gbase[m1 * 256 + j * 16];

      // ---- step s0: frags, 32 MFMA
      #pragma unroll
      for (int i = 0; i < 4; ++i) {
        bx[i] = *(const s16x8*)(b0 + (offX + i * 2048));
        by[i] = *(const s16x8*)(b0 + ((offX + i * 2048) ^ 64));
      }
      __builtin_amdgcn_s_setprio(1);
      #pragma unroll
      for (int i = 0; i < 4; ++i)
        #pragma unroll
        for (int j = 0; j < 4; ++j)
          MFMA_Z(accm[i][j], bx[i], areg[j][0]);
      #pragma unroll
      for (int i = 0; i < 4; ++i)
        #pragma unroll
        for (int j = 0; j < 4; ++j)
          MFMA_ACC(accm[i][j], by[i], areg[j][1]);
      __builtin_amdgcn_s_setprio(0);

      // ---- s1 frag reads (overlap s0 fold), then fold s0 (packed f32)
      #pragma unroll
      for (int i = 0; i < 4; ++i) {
        bx[i] = *(const s16x8*)(b1 + (offX + i * 2048));
        by[i] = *(const s16x8*)(b1 + ((offX + i * 2048) ^ 64));
      }
      #pragma unroll
      for (int i = 0; i < 4; ++i)
        #pragma unroll
        for (int j = 0; j < 4; ++j) {
          f32x2 g2 = {g0[j], g0[j]};
          f32x2* ap = (f32x2*)&acc[i][j];
          const f32x2* mp_ = (const f32x2*)&accm[i][j];
          ap[0] += g2 * mp_[0];
          ap[1] += g2 * mp_[1];
        }

      // ---- step s1: 32 MFMA, fold s1
      __builtin_amdgcn_s_setprio(1);
      #pragma unroll
      for (int i = 0; i < 4; ++i)
        #pragma unroll
        for (int j = 0; j < 4; ++j)
          MFMA_Z(accm[i][j], bx[i], areg[j][0]);
      #pragma unroll
      for (int i = 0; i < 4; ++i)
        #pragma unroll
        for (int j = 0; j < 4; ++j)
          MFMA_ACC(accm[i][j], by[i], areg[j][1]);
      __builtin_amdgcn_s_setprio(0);
      #pragma unroll
      for (int i = 0; i < 4; ++i)
        #pragma unroll
        for (int j = 0; j < 4; ++j) {
          f32x2 g2 = {g1[j], g1[j]};
          f32x2* ap = (f32x2*)&acc[i][j];
          const f32x2* mp_ = (const f32x2*)&accm[i][j];
          ap[0] += g2 * mp_[0];
          ap[1] += g2 * mp_[1];
        }

      // ---- region end: drain (loads were issued a full pair ago), barrier
      asm volatile("s_waitcnt vmcnt(0)" ::: "memory");
      __builtin_amdgcn_s_barrier();
    }
  }

  // ---- epilogue: acc[i][j][jj] = dzT[e][b]
  #pragma unroll
  for (int i = 0; i < 4; ++i) {
    int e = bcol * 128 + wc * 64 + i * 16 + ((lane >> 4) << 2);
    #pragma unroll
    for (int j = 0; j < 4; ++j) {
      size_t b = (size_t)brow * 256 + wr * 64 + j * 16 + lrow;
      *(f32x4*)(dz + b * D_N + e) = acc[i][j];
    }
  }
}

// ---------------------------------------------------------------------------
extern "C" void kernel_launch(void* const* d_in, const int* in_sizes, int n_in,
                              void* d_out, int out_size, void* d_ws, size_t ws_size,
                              hipStream_t stream) {
  const float* z   = (const float*)d_in[1];
  const float* Psi = (const float*)d_in[2];
  const float* gt  = (const float*)d_in[3];
  float* dz = (float*)d_out;

  // ws: wT 32KB | gatesb 512KB | Psib 8MB | zb16 16MB  (~24.5MB)
  float* wT = (float*)d_ws;
  unsigned short* gatesb = (unsigned short*)((char*)d_ws + 32768);
  short* Psib = (short*)((char*)d_ws + 32768 + 524288);
  short* zb16 = Psib + (size_t)M_N * D_N * D_N;

  k_trw <<<dim3(8, M_N), dim3(256), 0, stream>>>(Psi, gt, Psib, wT);
  k_gz  <<<dim3(B_N / 16), dim3(256), 0, stream>>>(z, wT, zb16, gatesb);
  k_gemm<<<dim3(256), dim3(512), 0, stream>>>((const char*)zb16, gatesb,
                                              (const char*)Psib, dz);
}

// Round 10
// 161.278 us; speedup vs baseline: 14.5352x; 1.1355x over previous
//
#include <hip/hip_runtime.h>
#include <hip/hip_bf16.h>

#define B_N 16384
#define D_N 512
#define M_N 16

typedef __attribute__((ext_vector_type(4))) float  f32x4;
typedef __attribute__((ext_vector_type(2))) float  f32x2;
typedef __attribute__((ext_vector_type(8))) short  s16x8;
typedef __attribute__((ext_vector_type(4))) unsigned short u16x4;

__device__ __forceinline__ short bf16_of(float f) {
  union { float f; unsigned u; } v; v.f = f;
  unsigned r = v.u + 0x7fffu + ((v.u >> 16) & 1u);  // RNE
  return (short)(r >> 16);
}
__device__ __forceinline__ float f32_of_bf16(unsigned short u) {
  union { unsigned u; float f; } v; v.u = ((unsigned)u) << 16; return v.f;
}
__device__ __forceinline__ void gload_lds16(const void* g, void* l) {
  __builtin_amdgcn_global_load_lds(
      (const __attribute__((address_space(1))) unsigned*)g,
      (__attribute__((address_space(3))) unsigned*)l, 16, 0, 0);
}

#define MFMA_ACC(d, x, y) d = __builtin_amdgcn_mfma_f32_16x16x32_bf16(x, y, d, 0, 0, 0)
#define MFMA_Z(d, x, y)   d = __builtin_amdgcn_mfma_f32_16x16x32_bf16(x, y, FZERO, 0, 0, 0)

// ---------------------------------------------------------------------------
// Kernel 1 (fused): Psib[m][e][d] = bf16(Psi[m][d][e]) pre-swizzled, AND
// wT[d,m] = sum_e Psi[m,d,e]*gt[m,e] (f32 exact path for gates).
// ---------------------------------------------------------------------------
__global__ void k_trw(const float* __restrict__ Psi, const float* __restrict__ gt,
                      short* __restrict__ Psib, float* __restrict__ wT) {
  int m = blockIdx.y, d0 = blockIdx.x << 6;
  __shared__ float tile[64][65];
  __shared__ float gs[D_N];
  int t = threadIdx.x;
  for (int i = t; i < D_N; i += 256) gs[i] = gt[m * D_N + i];
  int r = t >> 2, q = t & 3;
  float wacc = 0.f;
  const float* src = Psi + (size_t)m * D_N * D_N;
  short* dst = Psib + (size_t)m * D_N * D_N;
  for (int e0 = 0; e0 < D_N; e0 += 64) {
    __syncthreads();
    #pragma unroll
    for (int j = 0; j < 4; ++j) {
      int idx = t + (j << 8);
      int rr = idx >> 4, c4 = idx & 15;
      *(f32x4*)&tile[rr][c4 * 4] = *(const f32x4*)(src + (size_t)(d0 + rr) * D_N + e0 + c4 * 4);
    }
    __syncthreads();
    #pragma unroll
    for (int k = 0; k < 16; ++k) wacc += tile[r][q * 16 + k] * gs[e0 + q * 16 + k];
    #pragma unroll
    for (int it = 0; it < 2; ++it) {
      int idx = t + (it << 8);
      int el = idx >> 3, jb = idx & 7;
      int e = e0 + el;
      s16x8 o;
      #pragma unroll
      for (int k = 0; k < 8; ++k) o[k] = bf16_of(tile[jb * 8 + k][el]);
      int db = jb ^ (e & 7);
      *(s16x8*)(dst + (size_t)e * D_N + d0 + db * 8) = o;
    }
  }
  wacc += __shfl_xor(wacc, 1);
  wacc += __shfl_xor(wacc, 2);
  if (q == 0) wT[(d0 + r) * M_N + m] = wacc;
}

// ---------------------------------------------------------------------------
// Kernel 2 (fused): gates (bf16) + pre-swizzled bf16 z, one z read.
// ---------------------------------------------------------------------------
__global__ void k_gz(const float* __restrict__ z, const float* __restrict__ wT,
                     short* __restrict__ zb, unsigned short* __restrict__ gatesb) {
  __shared__ float zs[16][D_N];
  int t = threadIdx.x;
  size_t b0 = (size_t)blockIdx.x * 16;
  #pragma unroll
  for (int j = 0; j < 8; ++j) {
    int idx = t + (j << 8);
    int r = idx >> 7, c4 = idx & 127;
    *(f32x4*)&zs[r][c4 * 4] = *(const f32x4*)(z + (b0 + r) * D_N + c4 * 4);
  }
  __syncthreads();
  int r = t >> 4, m = t & 15;
  float s0 = 0.f, s1 = 0.f, s2 = 0.f, s3 = 0.f;
  #pragma unroll 4
  for (int e = 0; e < D_N; e += 4) {
    s0 += zs[r][e + 0] * wT[(e + 0) * M_N + m];
    s1 += zs[r][e + 1] * wT[(e + 1) * M_N + m];
    s2 += zs[r][e + 2] * wT[(e + 2) * M_N + m];
    s3 += zs[r][e + 3] * wT[(e + 3) * M_N + m];
  }
  float s = (s0 + s1) + (s2 + s3);
  float sig = 1.f / (1.f + expf(-s));
  gatesb[(b0 + r) * M_N + m] = (unsigned short)bf16_of(fmaxf(2.f * sig - 1.f, 0.f));
  #pragma unroll
  for (int j = 0; j < 4; ++j) {
    int idx = t + (j << 8);
    int rr = idx >> 6, blk = idx & 63;
    int chunk = blk >> 3, ib = blk & 7;
    int sb = ib ^ (rr & 7);
    const float* sp = &zs[rr][chunk * 64 + sb * 8];
    s16x8 o;
    #pragma unroll
    for (int k = 0; k < 8; ++k) o[k] = bf16_of(sp[k]);
    *(s16x8*)(zb + (b0 + rr) * D_N + blk * 8) = o;
  }
}

// ---------------------------------------------------------------------------
// Kernel 3: GEMM dz^T = sum_m g_m*(Psi_m^T @ z^T).  Round 10: 128b x 128e
// tile, 8 waves (4b x 2e), wave-tile 32b x 64e -> acc[4][2]+accm[4][2] = 64
// VGPR, total <=128 => TWO blocks per CU (16 waves). Independent blocks
// drift: one block's drain/fold overlaps the sibling's MFMA (m114 mechanism).
// Simple NBUF=2 per-step schedule, d-outer/m-inner, A-centric XCD map.
// LDS 72KB/block: A 2x16KB @0 | B 2x16KB @32768 | gates f32 8KB @65536.
// ---------------------------------------------------------------------------
__global__ __launch_bounds__(512, 4) void k_gemm(
    const char* __restrict__ zb, const unsigned short* __restrict__ gatesb,
    const char* __restrict__ pb, float* __restrict__ dz) {
  __shared__ __align__(128) char smem[73728];
  float* glf = (float*)(smem + 65536);

  const int tid = threadIdx.x;
  const int lane = tid & 63;
  const int wid = tid >> 6;            // 0..7
  const int wr = wid >> 1;             // b-group: 4 x 32 rows
  const int wc = wid & 1;              // e-group: 2 x 64 cols
  const int bid = blockIdx.x;          // 512 blocks
  const int xcd = bid & 7;
  const int g8 = bid >> 3;             // 0..63
  const int bcol = g8 & 3;
  const int brow = xcd * 16 + (g8 >> 2);  // 16 brow-slabs/XCD -> 2MB z, L2-fit

  // ---- gates -> LDS [m][128 rows] f32
  {
    int row = tid >> 2, g4 = tid & 3;
    u16x4 gv = *(const u16x4*)(gatesb + ((size_t)(brow * 128 + row) << 4) + (g4 << 2));
    #pragma unroll
    for (int k = 0; k < 4; ++k)
      glf[(g4 * 4 + k) * 128 + row] = f32_of_bf16(gv[k]);
  }

  const int rsub = lane >> 3, cbyte = (lane & 7) << 4;

  auto stageA = [&](int ab, int dc) {     // 2 loads: 128 rows x 128B d-chunk
    #pragma unroll
    for (int j = 0; j < 2; ++j) {
      const char* g = zb + (((size_t)(brow * 128 + wid * 8 + j * 64 + rsub)) << 10)
                      + (dc << 7) + cbyte;
      gload_lds16(g, smem + ab * 16384 + (wid << 10) + (j << 13));
    }
  };
  auto stageB = [&](int m, int dc, int qb) {  // 2 loads: 128 e-rows x 128B
    #pragma unroll
    for (int j = 0; j < 2; ++j) {
      const char* g = pb + (((size_t)(m * 512 + bcol * 128 + wid * 8 + j * 64 + rsub)) << 10)
                      + (dc << 7) + cbyte;
      gload_lds16(g, smem + 32768 + qb * 16384 + (wid << 10) + (j << 13));
    }
  };

  const int lrow = lane & 15;
  const int kq16 = (((lane >> 4) << 4)) ^ ((lrow & 7) << 4);
  const int offY = ((wr * 32 + lrow) << 7) + kq16;   // z frags (y operand)
  const int offX = ((wc * 64 + lrow) << 7) + kq16;   // Psi frags (x operand)
  const int grow = wr * 32 + lrow;                   // gate row base

  f32x4 acc[4][2] = {};
  f32x4 accm[4][2];
  s16x8 areg[2][2];
  const f32x4 FZERO = {0.f, 0.f, 0.f, 0.f};

  // ---- prologue: A(dc0), B(s=0); drain (covers gate ds_writes too); barrier
  stageA(0, 0);
  stageB(0, 0, 0);
  asm volatile("s_waitcnt vmcnt(0) lgkmcnt(0)" ::: "memory");
  __builtin_amdgcn_s_barrier();

  #pragma unroll 1
  for (int s = 0; s < 128; ++s) {
    const int m = s & 15, dc = s >> 4;

    // ---- issue next-tile stages first (latency cover under this step)
    if (s < 127) stageB((s + 1) & 15, (s + 1) >> 4, (s + 1) & 1);
    if (m == 14 && dc < 7) stageA((dc & 1) ^ 1, dc + 1);

    // ---- z frags once per d-chunk
    if (m == 0) {
      const char* abase = smem + (dc & 1) * 16384;
      #pragma unroll
      for (int j = 0; j < 2; ++j) {
        areg[j][0] = *(const s16x8*)(abase + (offY + j * 2048));
        areg[j][1] = *(const s16x8*)(abase + ((offY + j * 2048) ^ 64));
      }
    }
    float g0 = glf[m * 128 + grow];
    float g1 = glf[m * 128 + grow + 16];

    const char* bbase = smem + 32768 + (s & 1) * 16384;
    // ---- ks0: 4 frag reads + 8 MFMA (C=0)
    {
      s16x8 b0 = *(const s16x8*)(bbase + (offX));
      s16x8 b1 = *(const s16x8*)(bbase + (offX + 2048));
      s16x8 b2 = *(const s16x8*)(bbase + (offX + 4096));
      s16x8 b3 = *(const s16x8*)(bbase + (offX + 6144));
      __builtin_amdgcn_s_setprio(1);
      MFMA_Z(accm[0][0], b0, areg[0][0]); MFMA_Z(accm[0][1], b0, areg[1][0]);
      MFMA_Z(accm[1][0], b1, areg[0][0]); MFMA_Z(accm[1][1], b1, areg[1][0]);
      MFMA_Z(accm[2][0], b2, areg[0][0]); MFMA_Z(accm[2][1], b2, areg[1][0]);
      MFMA_Z(accm[3][0], b3, areg[0][0]); MFMA_Z(accm[3][1], b3, areg[1][0]);
      __builtin_amdgcn_s_setprio(0);
    }
    // ---- ks1: 4 frag reads + 8 MFMA (accumulate)
    {
      s16x8 b0 = *(const s16x8*)(bbase + (offX ^ 64));
      s16x8 b1 = *(const s16x8*)(bbase + ((offX + 2048) ^ 64));
      s16x8 b2 = *(const s16x8*)(bbase + ((offX + 4096) ^ 64));
      s16x8 b3 = *(const s16x8*)(bbase + ((offX + 6144) ^ 64));
      __builtin_amdgcn_s_setprio(1);
      MFMA_ACC(accm[0][0], b0, areg[0][1]); MFMA_ACC(accm[0][1], b0, areg[1][1]);
      MFMA_ACC(accm[1][0], b1, areg[0][1]); MFMA_ACC(accm[1][1], b1, areg[1][1]);
      MFMA_ACC(accm[2][0], b2, areg[0][1]); MFMA_ACC(accm[2][1], b2, areg[1][1]);
      MFMA_ACC(accm[3][0], b3, areg[0][1]); MFMA_ACC(accm[3][1], b3, areg[1][1]);
      __builtin_amdgcn_s_setprio(0);
    }
    // ---- gated fold (packed f32)
    #pragma unroll
    for (int i = 0; i < 4; ++i) {
      f32x2 ga = {g0, g0}, gb = {g1, g1};
      f32x2* a0 = (f32x2*)&acc[i][0];
      f32x2* a1 = (f32x2*)&acc[i][1];
      const f32x2* m0p = (const f32x2*)&accm[i][0];
      const f32x2* m1p = (const f32x2*)&accm[i][1];
      a0[0] += ga * m0p[0]; a0[1] += ga * m0p[1];
      a1[0] += gb * m1p[0]; a1[1] += gb * m1p[1];
    }

    asm volatile("s_waitcnt vmcnt(0)" ::: "memory");  // next tile landed
    __builtin_amdgcn_s_barrier();
  }

  // ---- epilogue: acc[i][j][jj] = dzT[e][b]
  #pragma unroll
  for (int i = 0; i < 4; ++i) {
    int e = bcol * 128 + wc * 64 + i * 16 + ((lane >> 4) << 2);
    #pragma unroll
    for (int j = 0; j < 2; ++j) {
      size_t b = (size_t)brow * 128 + wr * 32 + j * 16 + lrow;
      *(f32x4*)(dz + b * D_N + e) = acc[i][j];
    }
  }
}

// ---------------------------------------------------------------------------
extern "C" void kernel_launch(void* const* d_in, const int* in_sizes, int n_in,
                              void* d_out, int out_size, void* d_ws, size_t ws_size,
                              hipStream_t stream) {
  const float* z   = (const float*)d_in[1];
  const float* Psi = (const float*)d_in[2];
  const float* gt  = (const float*)d_in[3];
  float* dz = (float*)d_out;

  // ws: wT 32KB | gatesb 512KB | Psib 8MB | zb16 16MB  (~24.5MB)
  float* wT = (float*)d_ws;
  unsigned short* gatesb = (unsigned short*)((char*)d_ws + 32768);
  short* Psib = (short*)((char*)d_ws + 32768 + 524288);
  short* zb16 = Psib + (size_t)M_N * D_N * D_N;

  k_trw <<<dim3(8, M_N), dim3(256), 0, stream>>>(Psi, gt, Psib, wT);
  k_gz  <<<dim3(B_N / 16), dim3(256), 0, stream>>>(z, wT, zb16, gatesb);
  k_gemm<<<dim3(512), dim3(512), 0, stream>>>((const char*)zb16, gatesb,
                                              (const char*)Psib, dz);
}